// Round 10
// baseline (14240.179 us; speedup 1.0000x reference)
//
#include <hip/hip_runtime.h>
#include <cstdint>

// B=64 S=1024 D_IN=256 D_HID=512 D_LAT=128, GRU: 128->256->128, out 2
#define TOKENS 65536

// ---------------- ws layout (bytes), all f32 ----------------
#define WS_XL    0ULL
#define WS_HENC  67108864ULL
#define WS_GI0   0ULL
#define WS_XBUF0 201326592ULL                    // 131072 B (L0 exchange)
#define WS_XBUF1 (201326592ULL + 131072ULL)      // 65536 B  (L1 exchange)
#define WS_CNT   (201326592ULL + 196608ULL)      // 64 counters, 256B stride = 16384 B
#define WS_MUS   (201326592ULL + 212992ULL)
#define WS_MUT   (201326592ULL + 213504ULL)
#define WS_NEED  (201326592ULL + 214016ULL)
#define CNT_STRIDE 64                            // uints; 256B line pitch per counter

// ---------------- prep: fold BN into scale/shift ----------------
__global__ void k_prep(const float* __restrict__ bmu, const float* __restrict__ bng,
                       const float* __restrict__ bnb, const float* __restrict__ bnrm,
                       const float* __restrict__ bnrv,
                       float* __restrict__ mus, float* __restrict__ mut)
{
    int j = threadIdx.x;
    if (j < 128) {
        float s = bng[j] / sqrtf(bnrv[j] + 1e-5f);
        mus[j] = s;
        mut[j] = bmu[j] * s + bnb[j] - bnrm[j] * s;
    }
}

// ---------------- xl = log(softplus(x)), f32 ----------------
__global__ void k_xl(const float* __restrict__ x, float* __restrict__ xl, int n4)
{
    int i = blockIdx.x * blockDim.x + threadIdx.x;
    if (i >= n4) return;
    float4 v = ((const float4*)x)[i];
    float4 o;
    o.x = logf(v.x > 20.f ? v.x : log1pf(expf(v.x)));
    o.y = logf(v.y > 20.f ? v.y : log1pf(expf(v.y)));
    o.z = logf(v.z > 20.f ? v.z : log1pf(expf(v.z)));
    o.w = logf(v.w > 20.f ? v.w : log1pf(expf(v.w)));
    ((float4*)xl)[i] = o;
}

// ---------------- f32 tiled GEMM: C[m,n] = epi(acc*s[n] + t[n]) ----------------
// AZ=1: A computed on the fly as z = mu + eps*exp(0.5*lv)
template<int EPI, int AZ>
__global__ __launch_bounds__(256) void k_gemm_f32(
    const float* __restrict__ A, const float* __restrict__ W,
    const float* __restrict__ svec, const float* __restrict__ tvec,
    float* __restrict__ C, int N, int K,
    const float* __restrict__ ZMU, const float* __restrict__ ZLV, const float* __restrict__ ZEP)
{
    __shared__ float As[32][132];
    __shared__ float Ws[32][132];
    const int tid = threadIdx.x;
    const int tx = tid & 15, ty = tid >> 4;
    const int m0 = blockIdx.x * 128;
    const int n0 = blockIdx.y * 128;
    float acc[8][8];
#pragma unroll
    for (int i = 0; i < 8; ++i)
#pragma unroll
        for (int j = 0; j < 8; ++j) acc[i][j] = 0.f;

    for (int k0 = 0; k0 < K; k0 += 32) {
#pragma unroll
        for (int it = 0; it < 4; ++it) {
            int id = tid + 256 * it;
            int r = id >> 3, c4 = id & 7;
            float4 av;
            if constexpr (AZ) {
                size_t idx = (size_t)(m0 + r) * K + k0 + c4 * 4;
                float4 m4 = *(const float4*)(ZMU + idx);
                float4 l4 = *(const float4*)(ZLV + idx);
                float4 e4 = *(const float4*)(ZEP + idx);
                av.x = m4.x + e4.x * expf(0.5f * l4.x);
                av.y = m4.y + e4.y * expf(0.5f * l4.y);
                av.z = m4.z + e4.z * expf(0.5f * l4.z);
                av.w = m4.w + e4.w * expf(0.5f * l4.w);
            } else {
                av = *(const float4*)(A + (size_t)(m0 + r) * K + k0 + c4 * 4);
            }
            float4 wv = *(const float4*)(W + (size_t)(n0 + r) * K + k0 + c4 * 4);
            As[c4*4+0][r] = av.x; As[c4*4+1][r] = av.y; As[c4*4+2][r] = av.z; As[c4*4+3][r] = av.w;
            Ws[c4*4+0][r] = wv.x; Ws[c4*4+1][r] = wv.y; Ws[c4*4+2][r] = wv.z; Ws[c4*4+3][r] = wv.w;
        }
        __syncthreads();
#pragma unroll
        for (int k = 0; k < 32; ++k) {
            float4 a0 = *(const float4*)&As[k][ty*8];
            float4 a1 = *(const float4*)&As[k][ty*8+4];
            float4 w0 = *(const float4*)&Ws[k][tx*8];
            float4 w1 = *(const float4*)&Ws[k][tx*8+4];
            float ar[8] = {a0.x,a0.y,a0.z,a0.w,a1.x,a1.y,a1.z,a1.w};
            float wr[8] = {w0.x,w0.y,w0.z,w0.w,w1.x,w1.y,w1.z,w1.w};
#pragma unroll
            for (int i = 0; i < 8; ++i)
#pragma unroll
                for (int j = 0; j < 8; ++j) acc[i][j] += ar[i] * wr[j];
        }
        __syncthreads();
    }
#pragma unroll
    for (int i = 0; i < 8; ++i) {
        size_t m = (size_t)m0 + ty*8 + i;
#pragma unroll
        for (int j4 = 0; j4 < 2; ++j4) {
            float o[4];
#pragma unroll
            for (int j = 0; j < 4; ++j) {
                int col = n0 + tx*8 + j4*4 + j;
                float v = acc[i][j4*4+j];
                if (svec) v *= svec[col];
                v += tvec[col];
                if constexpr (EPI == 1) v = fmaxf(v, 0.f);
                if constexpr (EPI == 2) v = fminf(fmaxf(v, -10.f), 10.f);
                if constexpr (EPI == 3) v = expf(v);
                o[j] = v;
            }
            *(float4*)(C + m * N + n0 + tx*8 + j4*4) = *(float4*)o;
        }
    }
}

// ============ cross-block exchange: relaxed agent atomics, padded counters ============
__device__ __forceinline__ void xstore(float* p, float v) {
    __hip_atomic_store(p, v, __ATOMIC_RELAXED, __HIP_MEMORY_SCOPE_AGENT);
}
__device__ __forceinline__ float xload(const float* p) {
    return __hip_atomic_load(p, __ATOMIC_RELAXED, __HIP_MEMORY_SCOPE_AGENT);
}
__device__ __forceinline__ void xsync(unsigned* cb, unsigned tgt) {
    asm volatile("s_waitcnt vmcnt(0)" ::: "memory");
    __hip_atomic_fetch_add(cb, 1u, __ATOMIC_RELAXED, __HIP_MEMORY_SCOPE_AGENT);
    int guard = 0;
    while (__hip_atomic_load(cb, __ATOMIC_RELAXED, __HIP_MEMORY_SCOPE_AGENT) < tgt) {
        __builtin_amdgcn_s_sleep(2);
        if (++guard > (1 << 17)) break;   // bounded: fails measurably, not a hang
    }
    asm volatile("" ::: "memory");
}

// ---------------- fused pipelined scan: 256 blocks (4/batch), 256 threads ----------------
// Iteration u: L0 dots for t=u (VGPR-resident Whh0 quarter, threads 0..191)
//              || L1 dots for t=u-1 (wave 3 streams Wih1/Whh1 rows from L2)
//              || gi0[u] loads (wave 3, issued first).
// One exchange round per iteration carries L0 hn (256) + L1 hn (128); each block
// replays LN0 then LN1 (frozen round-4/7 FP sequences, bit-exact). No h0 stream.
__global__ __launch_bounds__(256)
__attribute__((amdgpu_waves_per_eu(1, 1)))
void k_scan_fused(const float* gi0, const float* wh0, const float* bhh0,
                  const float* wi1, const float* wh1,
                  const float* bih1, const float* bhh1,
                  const float* lg0, const float* lb0,
                  const float* lg1, const float* lb1,
                  const float* fcW, const float* fcb,
                  float* vout, float* xb0, float* xb1, unsigned* cnt)
{
    const int xcd  = blockIdx.x & 7;
    const int slot = blockIdx.x >> 3;       // 0..31
    const int b    = xcd * 8 + (slot >> 2); // 4 blocks of b share one XCD L2
    const int q    = slot & 3;
    const int tid  = threadIdx.x;
    const int lane = tid & 63;
    const int wvi  = tid >> 6;

    __shared__ float s_h0[256];
    __shared__ float s_h1[128];
    __shared__ float s_g0[192];
    __shared__ float s_g1i[96];
    __shared__ float s_g1h[96];
    __shared__ float s_r1[4], s_r2[4];

    // --- L0 resident weights (threads 0..191), frozen scan0 layout ---
    int row = 0;
    if (tid < 192)
        row = (tid < 64) ? (64*q + tid)
            : (tid < 128) ? (256 + 64*q + (tid-64))
                          : (512 + 64*q + (tid-128));
    float4 wr[64];
    float bA = 0.f;
    if (tid < 192) {
        const float4* p = (const float4*)(wh0 + (size_t)row * 256);
#pragma unroll
        for (int i = 0; i < 64; ++i) wr[i] = p[i];
        bA = bhh0[row];
    }
    // --- L1 streamed row pointers (wave 3) ---
    // lane<32: ih rows of unit 32q+lane; lane>=32: hh rows of unit 32q+(lane-32)
    const float4* w1p0 = nullptr; const float4* w1p1 = nullptr; const float4* w1p2 = nullptr;
    float b1r0 = 0.f, b1r1 = 0.f, b1r2 = 0.f;
    if (tid >= 192) {
        if (lane < 32) {
            int u1 = 32*q + lane;
            w1p0 = (const float4*)(wi1 + (size_t)(u1)       * 256);
            w1p1 = (const float4*)(wi1 + (size_t)(128 + u1) * 256);
            w1p2 = (const float4*)(wi1 + (size_t)(256 + u1) * 256);
            b1r0 = bih1[u1]; b1r1 = bih1[128 + u1]; b1r2 = bih1[256 + u1];
        } else {
            int u1 = 32*q + (lane - 32);
            w1p0 = (const float4*)(wh1 + (size_t)(u1)       * 128);
            w1p1 = (const float4*)(wh1 + (size_t)(128 + u1) * 128);
            w1p2 = (const float4*)(wh1 + (size_t)(256 + u1) * 128);
            b1r0 = bhh1[u1]; b1r1 = bhh1[128 + u1]; b1r2 = bhh1[256 + u1];
        }
    }
    const float gv0 = lg0[tid], bv0 = lb0[tid];
    float gv1 = 0.f, bv1 = 0.f;
    if (tid < 128) { gv1 = lg1[tid]; bv1 = lb1[tid]; s_h1[tid] = 0.f; }
    s_h0[tid] = 0.f;
    __syncthreads();

    const float* gbase = gi0 + (size_t)b * 1024 * 768;
    unsigned* cb = cnt + (size_t)b * CNT_STRIDE;

    for (int u = 0; u < 1024; ++u) {
        float gr = 0.f, gz = 0.f, gn = 0.f;
        if (tid < 192) {
            // frozen L0 dot: groups ascending, x->a0 y->a1 z->a2 w->a3, (a0+a1)+(a2+a3)
            float a0 = bA, a1 = 0.f, a2 = 0.f, a3 = 0.f;
            const float4* H = (const float4*)s_h0;
#pragma unroll
            for (int i = 0; i < 64; ++i) {
                float4 h4 = H[i];
                a0 += wr[i].x * h4.x; a1 += wr[i].y * h4.y;
                a2 += wr[i].z * h4.z; a3 += wr[i].w * h4.w;
            }
            s_g0[tid] = (a0 + a1) + (a2 + a3);
        } else {
            // gi0[u] loads first (overlap), then streamed L1 dots for t=u-1
            const float* gt = gbase + (size_t)u * 768;
            int uu = 64*q + lane;
            gr = gt[uu]; gz = gt[256 + uu]; gn = gt[512 + uu];
            if (u > 0) {
                if (lane < 32) {
                    const float4* H = (const float4*)s_h0;   // h0[u-1]
                    float r0a0=b1r0, r0a1=0.f, r0a2=0.f, r0a3=0.f;
                    float r1a0=b1r1, r1a1=0.f, r1a2=0.f, r1a3=0.f;
                    float r2a0=b1r2, r2a1=0.f, r2a2=0.f, r2a3=0.f;
#pragma unroll 8
                    for (int i = 0; i < 64; ++i) {
                        float4 h4 = H[i];
                        float4 w0 = w1p0[i], w1 = w1p1[i], w2 = w1p2[i];
                        r0a0 += w0.x*h4.x; r0a1 += w0.y*h4.y; r0a2 += w0.z*h4.z; r0a3 += w0.w*h4.w;
                        r1a0 += w1.x*h4.x; r1a1 += w1.y*h4.y; r1a2 += w1.z*h4.z; r1a3 += w1.w*h4.w;
                        r2a0 += w2.x*h4.x; r2a1 += w2.y*h4.y; r2a2 += w2.z*h4.z; r2a3 += w2.w*h4.w;
                    }
                    s_g1i[lane]      = (r0a0 + r0a1) + (r0a2 + r0a3);
                    s_g1i[32 + lane] = (r1a0 + r1a1) + (r1a2 + r1a3);
                    s_g1i[64 + lane] = (r2a0 + r2a1) + (r2a2 + r2a3);
                } else {
                    int l2 = lane - 32;
                    const float4* H = (const float4*)s_h1;   // h1[u-2]
                    float r0a0=b1r0, r0a1=0.f, r0a2=0.f, r0a3=0.f;
                    float r1a0=b1r1, r1a1=0.f, r1a2=0.f, r1a3=0.f;
                    float r2a0=b1r2, r2a1=0.f, r2a2=0.f, r2a3=0.f;
#pragma unroll 8
                    for (int i = 0; i < 32; ++i) {
                        float4 h4 = H[i];
                        float4 w0 = w1p0[i], w1 = w1p1[i], w2 = w1p2[i];
                        r0a0 += w0.x*h4.x; r0a1 += w0.y*h4.y; r0a2 += w0.z*h4.z; r0a3 += w0.w*h4.w;
                        r1a0 += w1.x*h4.x; r1a1 += w1.y*h4.y; r1a2 += w1.z*h4.z; r1a3 += w1.w*h4.w;
                        r2a0 += w2.x*h4.x; r2a1 += w2.y*h4.y; r2a2 += w2.z*h4.z; r2a3 += w2.w*h4.w;
                    }
                    s_g1h[l2]      = (r0a0 + r0a1) + (r0a2 + r0a3);
                    s_g1h[32 + l2] = (r1a0 + r1a1) + (r1a2 + r1a3);
                    s_g1h[64 + l2] = (r2a0 + r2a1) + (r2a2 + r2a3);
                }
            }
        }
        __syncthreads();                                  // B1
        // --- gates: L0 by wave 3 (frozen scan0), L1 by wave-2 lanes 0..31 (frozen scan1) ---
        float* xw0 = xb0 + (((size_t)b * 2 + (u & 1)) * 4 + q) * 64;
        float* xw1 = xb1 + (((size_t)b * 2 + (u & 1)) * 4 + q) * 32;
        if (tid >= 192) {
            int g = lane;
            int uu = 64*q + g;
            float r  = 1.f / (1.f + expf(-(gr + s_g0[g])));
            float zg = 1.f / (1.f + expf(-(gz + s_g0[64 + g])));
            float nn = tanhf(gn + r * s_g0[128 + g]);
            float hn = (1.f - zg) * nn + zg * s_h0[uu];
            xstore(&xw0[g], hn);
        } else if (tid >= 128 && tid < 160 && u > 0) {
            int g = tid - 128;
            int uu = 32*q + g;
            float r  = 1.f / (1.f + expf(-(s_g1i[g]      + s_g1h[g])));
            float zg = 1.f / (1.f + expf(-(s_g1i[32 + g] + s_g1h[32 + g])));
            float nn = tanhf(s_g1i[64 + g] + r * s_g1h[64 + g]);
            float hn = (1.f - zg) * nn + zg * s_h1[uu];
            xstore(&xw1[g], hn);
        }
        __syncthreads();                                  // B2: drains all stores
        if (tid == 0) xsync(cb, 4u * (unsigned)(u + 1));
        __syncthreads();                                  // B3
        // --- read exchanged values ---
        const float* xr0 = xb0 + (((size_t)b * 2 + (u & 1)) * 4) * 64;
        const float* xr1 = xb1 + (((size_t)b * 2 + (u & 1)) * 4) * 32;
        float hn0 = xload(&xr0[tid]);
        float hn1 = 0.f;
        if (tid < 128 && u > 0) hn1 = xload(&xr1[tid]);
        // --- LN0 replay (frozen round-4 sequence) ---
        {
            float sum = hn0;
#pragma unroll
            for (int o = 32; o > 0; o >>= 1) sum += __shfl_xor(sum, o);
            if (lane == 0) s_r1[wvi] = sum;
        }
        __syncthreads();
        float m0v = (s_r1[0] + s_r1[1] + s_r1[2] + s_r1[3]) * (1.f / 256.f);
        float d0 = hn0 - m0v;
        {
            float ss = d0 * d0;
#pragma unroll
            for (int o = 32; o > 0; o >>= 1) ss += __shfl_xor(ss, o);
            if (lane == 0) s_r2[wvi] = ss;
        }
        __syncthreads();
        float va0 = (s_r2[0] + s_r2[1] + s_r2[2] + s_r2[3]) * (1.f / 256.f);
        float rs0 = 1.f / sqrtf(va0 + 1e-5f);
        float hl0 = d0 * rs0 * gv0 + bv0;
        __syncthreads();                                  // s_r reuse fence
        s_h0[tid] = hl0;
        // --- LN1 replay (frozen scan1 sequence) ---
        if (u > 0) {
            float d1 = 0.f;
            if (tid < 128) {
                float sum = hn1;
#pragma unroll
                for (int o = 32; o > 0; o >>= 1) sum += __shfl_xor(sum, o);
                if (lane == 0) s_r1[wvi] = sum;
            }
            __syncthreads();
            if (tid < 128) {
                float m1 = (s_r1[0] + s_r1[1]) * (1.f / 128.f);
                d1 = hn1 - m1;
                float ss = d1 * d1;
#pragma unroll
                for (int o = 32; o > 0; o >>= 1) ss += __shfl_xor(ss, o);
                if (lane == 0) s_r2[wvi] = ss;
            }
            __syncthreads();
            if (tid < 128) {
                float va1 = (s_r2[0] + s_r2[1]) * (1.f / 128.f);
                float rs1 = 1.f / sqrtf(va1 + 1e-5f);
                s_h1[tid] = d1 * rs1 * gv1 + bv1;
            }
        }
        __syncthreads();                                  // B4
    }
    // ---- epilogue: L1 for t=1023 (h0[1023] in s_h0, h1[1022] in s_h1) ----
    if (tid >= 192) {
        if (lane < 32) {
            const float4* H = (const float4*)s_h0;
            float r0a0=b1r0, r0a1=0.f, r0a2=0.f, r0a3=0.f;
            float r1a0=b1r1, r1a1=0.f, r1a2=0.f, r1a3=0.f;
            float r2a0=b1r2, r2a1=0.f, r2a2=0.f, r2a3=0.f;
#pragma unroll 8
            for (int i = 0; i < 64; ++i) {
                float4 h4 = H[i];
                float4 w0 = w1p0[i], w1 = w1p1[i], w2 = w1p2[i];
                r0a0 += w0.x*h4.x; r0a1 += w0.y*h4.y; r0a2 += w0.z*h4.z; r0a3 += w0.w*h4.w;
                r1a0 += w1.x*h4.x; r1a1 += w1.y*h4.y; r1a2 += w1.z*h4.z; r1a3 += w1.w*h4.w;
                r2a0 += w2.x*h4.x; r2a1 += w2.y*h4.y; r2a2 += w2.z*h4.z; r2a3 += w2.w*h4.w;
            }
            s_g1i[lane]      = (r0a0 + r0a1) + (r0a2 + r0a3);
            s_g1i[32 + lane] = (r1a0 + r1a1) + (r1a2 + r1a3);
            s_g1i[64 + lane] = (r2a0 + r2a1) + (r2a2 + r2a3);
        } else {
            int l2 = lane - 32;
            const float4* H = (const float4*)s_h1;
            float r0a0=b1r0, r0a1=0.f, r0a2=0.f, r0a3=0.f;
            float r1a0=b1r1, r1a1=0.f, r1a2=0.f, r1a3=0.f;
            float r2a0=b1r2, r2a1=0.f, r2a2=0.f, r2a3=0.f;
#pragma unroll 8
            for (int i = 0; i < 32; ++i) {
                float4 h4 = H[i];
                float4 w0 = w1p0[i], w1 = w1p1[i], w2 = w1p2[i];
                r0a0 += w0.x*h4.x; r0a1 += w0.y*h4.y; r0a2 += w0.z*h4.z; r0a3 += w0.w*h4.w;
                r1a0 += w1.x*h4.x; r1a1 += w1.y*h4.y; r1a2 += w1.z*h4.z; r1a3 += w1.w*h4.w;
                r2a0 += w2.x*h4.x; r2a1 += w2.y*h4.y; r2a2 += w2.z*h4.z; r2a3 += w2.w*h4.w;
            }
            s_g1h[l2]      = (r0a0 + r0a1) + (r0a2 + r0a3);
            s_g1h[32 + l2] = (r1a0 + r1a1) + (r1a2 + r1a3);
            s_g1h[64 + l2] = (r2a0 + r2a1) + (r2a2 + r2a3);
        }
    }
    __syncthreads();
    {
        float* xw1 = xb1 + (((size_t)b * 2 + 0) * 4 + q) * 32;   // parity 1024&1 = 0
        if (tid >= 128 && tid < 160) {
            int g = tid - 128;
            int uu = 32*q + g;
            float r  = 1.f / (1.f + expf(-(s_g1i[g]      + s_g1h[g])));
            float zg = 1.f / (1.f + expf(-(s_g1i[32 + g] + s_g1h[32 + g])));
            float nn = tanhf(s_g1i[64 + g] + r * s_g1h[64 + g]);
            float hn = (1.f - zg) * nn + zg * s_h1[uu];
            xstore(&xw1[g], hn);
        }
    }
    __syncthreads();
    if (tid == 0) xsync(cb, 4u * 1025u);
    __syncthreads();
    {
        const float* xr1 = xb1 + (((size_t)b * 2 + 0) * 4) * 32;
        float hn1 = 0.f, d1 = 0.f;
        if (tid < 128) {
            hn1 = xload(&xr1[tid]);
            float sum = hn1;
#pragma unroll
            for (int o = 32; o > 0; o >>= 1) sum += __shfl_xor(sum, o);
            if (lane == 0) s_r1[wvi] = sum;
        }
        __syncthreads();
        if (tid < 128) {
            float m1 = (s_r1[0] + s_r1[1]) * (1.f / 128.f);
            d1 = hn1 - m1;
            float ss = d1 * d1;
#pragma unroll
            for (int o = 32; o > 0; o >>= 1) ss += __shfl_xor(ss, o);
            if (lane == 0) s_r2[wvi] = ss;
        }
        __syncthreads();
        if (tid < 128) {
            float va1 = (s_r2[0] + s_r2[1]) * (1.f / 128.f);
            float rs1 = 1.f / sqrtf(va1 + 1e-5f);
            s_h1[tid] = d1 * rs1 * gv1 + bv1;
        }
    }
    __syncthreads();
    // ---- fc head (frozen scan1 sequence) ----
    float p0 = 0.f, p1 = 0.f;
    if (tid < 128) {
        float hold = s_h1[tid];
        p0 = fcW[tid] * hold;
        p1 = fcW[128 + tid] * hold;
#pragma unroll
        for (int o = 32; o > 0; o >>= 1) { p0 += __shfl_xor(p0, o); p1 += __shfl_xor(p1, o); }
        if (lane == 0) { s_r1[wvi] = p0; s_r2[wvi] = p1; }
    }
    __syncthreads();
    if (tid == 0 && q == 0) {
        vout[b * 2 + 0] = s_r1[0] + s_r1[1] + fcb[0];
        vout[b * 2 + 1] = s_r2[0] + s_r2[1] + fcb[1];
    }
}

// ---------------- launcher ----------------
extern "C" void kernel_launch(void* const* d_in, const int* in_sizes, int n_in,
                              void* d_out, int out_size, void* d_ws, size_t ws_size,
                              hipStream_t stream)
{
    const float* x     = (const float*)d_in[0];
    const float* eps   = (const float*)d_in[1];
    const float* W1lv  = (const float*)d_in[2];
    const float* b1lv  = (const float*)d_in[3];
    const float* W2lv  = (const float*)d_in[4];
    const float* b2lv  = (const float*)d_in[5];
    const float* Wmu   = (const float*)d_in[6];
    const float* bmu   = (const float*)d_in[7];
    const float* bn_g  = (const float*)d_in[8];
    const float* bn_b  = (const float*)d_in[9];
    const float* bn_rm = (const float*)d_in[10];
    const float* bn_rv = (const float*)d_in[11];
    const float* Wdec  = (const float*)d_in[12];
    const float* bdec  = (const float*)d_in[13];
    const float* Wih0  = (const float*)d_in[14];
    const float* Whh0  = (const float*)d_in[15];
    const float* bih0  = (const float*)d_in[16];
    const float* bhh0  = (const float*)d_in[17];
    const float* Wih1  = (const float*)d_in[18];
    const float* Whh1  = (const float*)d_in[19];
    const float* bih1  = (const float*)d_in[20];
    const float* bhh1  = (const float*)d_in[21];
    const float* ln_g0 = (const float*)d_in[22];
    const float* ln_b0 = (const float*)d_in[23];
    const float* ln_g1 = (const float*)d_in[24];
    const float* ln_b1 = (const float*)d_in[25];
    const float* fc_W  = (const float*)d_in[26];
    const float* fc_b  = (const float*)d_in[27];

    float* out   = (float*)d_out;
    float* v_out = out;                                   // [64,2]
    float* xrec  = out + 128;                             // [64,1024,256]
    float* mu    = out + 128 + 16777216;                  // [64,1024,128]
    float* lv    = out + 128 + 16777216 + 8388608;        // [64,1024,128]

    if (ws_size < WS_NEED) return;  // distinctive failure: outputs stay zero
    char* ws = (char*)d_ws;
    float*    XL    = (float*)(ws + WS_XL);
    float*    HENC  = (float*)(ws + WS_HENC);
    float*    GI0   = (float*)(ws + WS_GI0);    // overlays XL+HENC (dead by then)
    float*    XBUF0 = (float*)(ws + WS_XBUF0);
    float*    XBUF1 = (float*)(ws + WS_XBUF1);
    unsigned* CNT0  = (unsigned*)(ws + WS_CNT);
    float*    MUS   = (float*)(ws + WS_MUS);
    float*    MUT   = (float*)(ws + WS_MUT);

    k_prep<<<1, 128, 0, stream>>>(bmu, bn_g, bn_b, bn_rm, bn_rv, MUS, MUT);
    k_xl<<<16384, 256, 0, stream>>>(x, XL, 4194304);
    // encoder
    k_gemm_f32<1,0><<<dim3(512, 4), 256, 0, stream>>>(XL,   W1lv, nullptr, b1lv, HENC, 512, 256, nullptr, nullptr, nullptr);
    k_gemm_f32<0,0><<<dim3(512, 1), 256, 0, stream>>>(HENC, W2lv, nullptr, b2lv, lv,   128, 512, nullptr, nullptr, nullptr);
    k_gemm_f32<2,0><<<dim3(512, 1), 256, 0, stream>>>(XL,   Wmu,  MUS,     MUT,  mu,   128, 256, nullptr, nullptr, nullptr);
    // gi0 GEMM with fused reparameterization (XL/HENC dead -> GI0 overlays them)
    k_gemm_f32<0,1><<<dim3(512, 6), 256, 0, stream>>>(nullptr, Wih0, nullptr, bih0, GI0, 768, 128, mu, lv, eps);
    // decoder with fused reparameterization
    k_gemm_f32<3,1><<<dim3(512, 2), 256, 0, stream>>>(nullptr, Wdec, nullptr, bdec, xrec, 256, 128, mu, lv, eps);
    // reset exchange counters (per launch, graph-capture-safe)
    hipMemsetAsync(CNT0, 0, 16384, stream);
    // fused pipelined scan (both GRU layers, one sync round per step)
    k_scan_fused<<<256, 256, 0, stream>>>(GI0, Whh0, bhh0, Wih1, Whh1, bih1, bhh1,
                                          ln_g0, ln_b0, ln_g1, ln_b1, fc_W, fc_b,
                                          v_out, XBUF0, XBUF1, CNT0);
}

// Round 11
// 8465.929 us; speedup vs baseline: 1.6821x; 1.6821x over previous
//
#include <hip/hip_runtime.h>
#include <cstdint>

// B=64 S=1024 D_IN=256 D_HID=512 D_LAT=128, GRU: 128->256->128, out 2
#define TOKENS 65536

// ---------------- ws layout (bytes), all f32 ----------------
#define WS_XL    0ULL
#define WS_HENC  67108864ULL
#define WS_GI0   0ULL
#define WS_XBUF0 201326592ULL                    // 131072 B
#define WS_XBUF1 (201326592ULL + 131072ULL)      // 65536 B
#define WS_CNT   (201326592ULL + 196608ULL)      // 2*64 counters, 256B stride = 32768 B
#define WS_MUS   (201326592ULL + 229376ULL)
#define WS_MUT   (201326592ULL + 229888ULL)
#define WS_NEED  (201326592ULL + 230400ULL)
#define CNT_STRIDE 64                            // uints; 256B line pitch per counter

// ---------------- prep: fold BN into scale/shift ----------------
__global__ void k_prep(const float* __restrict__ bmu, const float* __restrict__ bng,
                       const float* __restrict__ bnb, const float* __restrict__ bnrm,
                       const float* __restrict__ bnrv,
                       float* __restrict__ mus, float* __restrict__ mut)
{
    int j = threadIdx.x;
    if (j < 128) {
        float s = bng[j] / sqrtf(bnrv[j] + 1e-5f);
        mus[j] = s;
        mut[j] = bmu[j] * s + bnb[j] - bnrm[j] * s;
    }
}

// ---------------- xl = log(softplus(x)), f32 ----------------
__global__ void k_xl(const float* __restrict__ x, float* __restrict__ xl, int n4)
{
    int i = blockIdx.x * blockDim.x + threadIdx.x;
    if (i >= n4) return;
    float4 v = ((const float4*)x)[i];
    float4 o;
    o.x = logf(v.x > 20.f ? v.x : log1pf(expf(v.x)));
    o.y = logf(v.y > 20.f ? v.y : log1pf(expf(v.y)));
    o.z = logf(v.z > 20.f ? v.z : log1pf(expf(v.z)));
    o.w = logf(v.w > 20.f ? v.w : log1pf(expf(v.w)));
    ((float4*)xl)[i] = o;
}

// ---------------- f32 tiled GEMM: C[m,n] = epi(acc*s[n] + t[n]) ----------------
// AZ=1: A computed on the fly as z = mu + eps*exp(0.5*lv)
template<int EPI, int AZ>
__global__ __launch_bounds__(256) void k_gemm_f32(
    const float* __restrict__ A, const float* __restrict__ W,
    const float* __restrict__ svec, const float* __restrict__ tvec,
    float* __restrict__ C, int N, int K,
    const float* __restrict__ ZMU, const float* __restrict__ ZLV, const float* __restrict__ ZEP)
{
    __shared__ float As[32][132];
    __shared__ float Ws[32][132];
    const int tid = threadIdx.x;
    const int tx = tid & 15, ty = tid >> 4;
    const int m0 = blockIdx.x * 128;
    const int n0 = blockIdx.y * 128;
    float acc[8][8];
#pragma unroll
    for (int i = 0; i < 8; ++i)
#pragma unroll
        for (int j = 0; j < 8; ++j) acc[i][j] = 0.f;

    for (int k0 = 0; k0 < K; k0 += 32) {
#pragma unroll
        for (int it = 0; it < 4; ++it) {
            int id = tid + 256 * it;
            int r = id >> 3, c4 = id & 7;
            float4 av;
            if constexpr (AZ) {
                size_t idx = (size_t)(m0 + r) * K + k0 + c4 * 4;
                float4 m4 = *(const float4*)(ZMU + idx);
                float4 l4 = *(const float4*)(ZLV + idx);
                float4 e4 = *(const float4*)(ZEP + idx);
                av.x = m4.x + e4.x * expf(0.5f * l4.x);
                av.y = m4.y + e4.y * expf(0.5f * l4.y);
                av.z = m4.z + e4.z * expf(0.5f * l4.z);
                av.w = m4.w + e4.w * expf(0.5f * l4.w);
            } else {
                av = *(const float4*)(A + (size_t)(m0 + r) * K + k0 + c4 * 4);
            }
            float4 wv = *(const float4*)(W + (size_t)(n0 + r) * K + k0 + c4 * 4);
            As[c4*4+0][r] = av.x; As[c4*4+1][r] = av.y; As[c4*4+2][r] = av.z; As[c4*4+3][r] = av.w;
            Ws[c4*4+0][r] = wv.x; Ws[c4*4+1][r] = wv.y; Ws[c4*4+2][r] = wv.z; Ws[c4*4+3][r] = wv.w;
        }
        __syncthreads();
#pragma unroll
        for (int k = 0; k < 32; ++k) {
            float4 a0 = *(const float4*)&As[k][ty*8];
            float4 a1 = *(const float4*)&As[k][ty*8+4];
            float4 w0 = *(const float4*)&Ws[k][tx*8];
            float4 w1 = *(const float4*)&Ws[k][tx*8+4];
            float ar[8] = {a0.x,a0.y,a0.z,a0.w,a1.x,a1.y,a1.z,a1.w};
            float wr[8] = {w0.x,w0.y,w0.z,w0.w,w1.x,w1.y,w1.z,w1.w};
#pragma unroll
            for (int i = 0; i < 8; ++i)
#pragma unroll
                for (int j = 0; j < 8; ++j) acc[i][j] += ar[i] * wr[j];
        }
        __syncthreads();
    }
#pragma unroll
    for (int i = 0; i < 8; ++i) {
        size_t m = (size_t)m0 + ty*8 + i;
#pragma unroll
        for (int j4 = 0; j4 < 2; ++j4) {
            float o[4];
#pragma unroll
            for (int j = 0; j < 4; ++j) {
                int col = n0 + tx*8 + j4*4 + j;
                float v = acc[i][j4*4+j];
                if (svec) v *= svec[col];
                v += tvec[col];
                if constexpr (EPI == 1) v = fmaxf(v, 0.f);
                if constexpr (EPI == 2) v = fminf(fmaxf(v, -10.f), 10.f);
                if constexpr (EPI == 3) v = expf(v);
                o[j] = v;
            }
            *(float4*)(C + m * N + n0 + tx*8 + j4*4) = *(float4*)o;
        }
    }
}

// ============ cross-block exchange: relaxed agent atomics, padded counters ============
__device__ __forceinline__ void xstore(float* p, float v) {
    __hip_atomic_store(p, v, __ATOMIC_RELAXED, __HIP_MEMORY_SCOPE_AGENT);
}
__device__ __forceinline__ float xload(const float* p) {
    return __hip_atomic_load(p, __ATOMIC_RELAXED, __HIP_MEMORY_SCOPE_AGENT);
}
__device__ __forceinline__ void xsync(unsigned* cb, unsigned tgt) {
    asm volatile("s_waitcnt vmcnt(0)" ::: "memory");
    __hip_atomic_fetch_add(cb, 1u, __ATOMIC_RELAXED, __HIP_MEMORY_SCOPE_AGENT);
    int guard = 0;
    while (__hip_atomic_load(cb, __ATOMIC_RELAXED, __HIP_MEMORY_SCOPE_AGENT) < tgt) {
        __builtin_amdgcn_s_sleep(2);
        if (++guard > (1 << 17)) break;   // bounded: fails measurably, not a hang
    }
    asm volatile("" ::: "memory");
}

// ---------------- scan layer 0: 256 blocks (4 per batch), 256 threads ----------------
__global__ __launch_bounds__(256)
__attribute__((amdgpu_waves_per_eu(1, 1)))
void k_scan0(const float* gi0, const float* wh0, const float* bhh0,
             const float* lg0, const float* lb0,
             float* h0s, float* xbuf, unsigned* cnt)
{
    const int xcd  = blockIdx.x & 7;
    const int slot = blockIdx.x >> 3;       // 0..31
    const int b    = xcd * 8 + (slot >> 2); // 4 blocks of b land on one XCD
    const int q    = slot & 3;
    const int tid = threadIdx.x;
    const int lane = tid & 63;
    const int wvi  = tid >> 6;

    __shared__ float s_h[256];
    __shared__ float s_g[192];
    __shared__ float s_r1[4], s_r2[4];

    int row = 0;
    if (tid < 192)
        row = (tid < 64) ? (64*q + tid)
            : (tid < 128) ? (256 + 64*q + (tid-64))
                          : (512 + 64*q + (tid-128));
    float4 wr[64];
    float bA = 0.f;
    if (tid < 192) {
        const float4* p = (const float4*)(wh0 + (size_t)row * 256);
#pragma unroll
        for (int i = 0; i < 64; ++i) wr[i] = p[i];
        bA = bhh0[row];
    }
    const float gv = lg0[tid], bv = lb0[tid];
    s_h[tid] = 0.f;
    __syncthreads();

    const float* gbase = gi0 + (size_t)b * 1024 * 768;
    float* hb = h0s + (size_t)b * 1024 * 256;
    unsigned* cb = cnt + (size_t)b * CNT_STRIDE;

    for (int t = 0; t < 1024; ++t) {
        float gr = 0.f, gz = 0.f, gn = 0.f;
        if (tid >= 192) {               // wave 3: issue gi0 loads under waves 0-2's dots
            const float* gt = gbase + (size_t)t * 768;
            int u = 64*q + (tid - 192);
            gr = gt[u]; gz = gt[256 + u]; gn = gt[512 + u];
        } else {
            // frozen round-4 dot: groups ascending, x->a0 y->a1 z->a2 w->a3, (a0+a1)+(a2+a3)
            float a0 = bA, a1 = 0.f, a2 = 0.f, a3 = 0.f;
            const float4* H = (const float4*)s_h;
#pragma unroll
            for (int i = 0; i < 64; ++i) {
                float4 h4 = H[i];
                a0 += wr[i].x * h4.x; a1 += wr[i].y * h4.y;
                a2 += wr[i].z * h4.z; a3 += wr[i].w * h4.w;
            }
            s_g[tid] = (a0 + a1) + (a2 + a3);
        }
        __syncthreads();                                  // B1
        float* xw = xbuf + (((size_t)b * 2 + (t & 1)) * 4 + q) * 64;
        if (tid >= 192) {
            int g = tid - 192;
            int u = 64*q + g;
            float r  = 1.f / (1.f + expf(-(gr + s_g[g])));
            float zg = 1.f / (1.f + expf(-(gz + s_g[64 + g])));
            float nn = tanhf(gn + r * s_g[128 + g]);
            float hn = (1.f - zg) * nn + zg * s_h[u];
            xstore(&xw[g], hn);
        }
        __syncthreads();                                  // B2: drains all waves' stores
        if (tid == 0) xsync(cb, 4u * (unsigned)(t + 1));
        __syncthreads();                                  // B3
        const float* xr = xbuf + (((size_t)b * 2 + (t & 1)) * 4) * 64;
        float hn = xload(&xr[tid]);
        float sum = hn;
#pragma unroll
        for (int o = 32; o > 0; o >>= 1) sum += __shfl_xor(sum, o);
        if (lane == 0) s_r1[wvi] = sum;
        __syncthreads();
        float m = (s_r1[0] + s_r1[1] + s_r1[2] + s_r1[3]) * (1.f / 256.f);
        float d = hn - m;
        float ss = d * d;
#pragma unroll
        for (int o = 32; o > 0; o >>= 1) ss += __shfl_xor(ss, o);
        if (lane == 0) s_r2[wvi] = ss;
        __syncthreads();
        float va = (s_r2[0] + s_r2[1] + s_r2[2] + s_r2[3]) * (1.f / 256.f);
        float rs = 1.f / sqrtf(va + 1e-5f);
        float hl = d * rs * gv + bv;
        s_h[tid] = hl;
        if (q == 0) hb[(size_t)t * 256 + tid] = hl;
        __syncthreads();                                  // B4
    }
}

// ---------------- scan layer 1: 256 blocks (4 per batch), 256 threads ----------------
// Round-11 change (load scheduling ONLY; all FP code identical to round 9):
// s_x is double-buffered; the h0[t+1] staging loads are issued at loop TOP
// (hidden under the dot phase) and written to the inactive buffer in the
// gates phase, instead of being issued late and drained exposed by B2.
__global__ __launch_bounds__(256)
__attribute__((amdgpu_waves_per_eu(1, 1)))
void k_scan1(const float* h0s, const float* wi1, const float* wh1,
             const float* bih1, const float* bhh1,
             const float* lg1, const float* lb1,
             const float* fcW, const float* fcb,
             float* vout, float* xbuf, unsigned* cnt)
{
    const int xcd  = blockIdx.x & 7;
    const int slot = blockIdx.x >> 3;
    const int b    = xcd * 8 + (slot >> 2);
    const int q    = slot & 3;
    const int tid = threadIdx.x;
    const int lane = tid & 63;
    const int wvi  = tid >> 6;

    __shared__ float s_x[2][256];
    __shared__ float s_h[128];
    __shared__ float s_g[768];
    __shared__ float s_r1[2], s_r2[2];

    float4 wr[64];
    float bB = 0.f;
    if (tid < 96) {
        int jj = tid;
        int row = (jj < 32) ? (32*q + jj) : (jj < 64) ? (128 + 32*q + (jj-32)) : (256 + 32*q + (jj-64));
        const float4* p = (const float4*)(wi1 + (size_t)row * 256);
#pragma unroll
        for (int i = 0; i < 64; ++i) wr[i] = p[i];
        bB = bih1[row];
    } else if (tid < 192) {
        int jj = tid - 96;
        int row = (jj < 32) ? (32*q + jj) : (jj < 64) ? (128 + 32*q + (jj-32)) : (256 + 32*q + (jj-64));
        const float4* p = (const float4*)(wh1 + (size_t)row * 128);
#pragma unroll
        for (int i = 0; i < 32; ++i) wr[i] = p[i];
        bB = bhh1[row];
    }
    float gv = 0.f, bv = 0.f;
    if (tid < 128) { gv = lg1[tid]; bv = lb1[tid]; s_h[tid] = 0.f; }
    const float4* xb4 = (const float4*)(h0s + (size_t)b * 1024 * 256);
    if (tid < 64) ((float4*)s_x[0])[tid] = xb4[tid];      // stage t=0
    __syncthreads();

    unsigned* cb = cnt + (size_t)b * CNT_STRIDE;

    for (int t = 0; t < 1024; ++t) {
        const int cur = t & 1, nxt = cur ^ 1;
        // early issue: h0[t+1] loads at loop top (hidden under the dot phase)
        float4 st0, st1;
        const bool stg = (tid >= 224) && (t + 1 < 1024);
        if (stg) {
            int k = tid - 224;
            st0 = xb4[(size_t)(t+1) * 64 + k];
            st1 = xb4[(size_t)(t+1) * 64 + k + 32];
        }
        if (tid < 96) {
            // frozen scan1 ih dot (identical FP sequence, reads s_x[cur])
            float a0 = bB, a1 = 0.f, a2 = 0.f, a3 = 0.f;
            const float4* X = (const float4*)s_x[cur];
#pragma unroll
            for (int i = 0; i < 64; ++i) {
                float4 h4 = X[i];
                a0 += wr[i].x * h4.x; a1 += wr[i].y * h4.y;
                a2 += wr[i].z * h4.z; a3 += wr[i].w * h4.w;
            }
            s_g[tid] = (a0 + a1) + (a2 + a3);
        } else if (tid < 192) {
            float a0 = bB, a1 = 0.f, a2 = 0.f, a3 = 0.f;
            const float4* Hh = (const float4*)s_h;
#pragma unroll
            for (int i = 0; i < 32; ++i) {
                float4 h4 = Hh[i];
                a0 += wr[i].x * h4.x; a1 += wr[i].y * h4.y;
                a2 += wr[i].z * h4.z; a3 += wr[i].w * h4.w;
            }
            s_g[96 + (tid - 96)] = (a0 + a1) + (a2 + a3);
        }
        __syncthreads();                                  // B1
        float* xw = xbuf + (((size_t)b * 2 + (t & 1)) * 4 + q) * 32;
        if (tid >= 192 && tid < 224) {
            int g = tid - 192;
            int u = 32*q + g;
            float r  = 1.f / (1.f + expf(-(s_g[g]      + s_g[96 + g])));
            float zg = 1.f / (1.f + expf(-(s_g[32 + g] + s_g[128 + g])));
            float nn = tanhf(s_g[64 + g] + r * s_g[160 + g]);
            float hn = (1.f - zg) * nn + zg * s_h[u];
            xstore(&xw[g], hn);
        } else if (stg) {                                 // write staged h0[t+1]
            int k = tid - 224;
            ((float4*)s_x[nxt])[k]      = st0;
            ((float4*)s_x[nxt])[k + 32] = st1;
        }
        __syncthreads();                                  // B2
        if (tid == 0) xsync(cb, 4u * (unsigned)(t + 1));
        __syncthreads();                                  // B3
        const float* xr = xbuf + (((size_t)b * 2 + (t & 1)) * 4) * 32;
        float hn = 0.f, d = 0.f;
        if (tid < 128) {
            hn = xload(&xr[tid]);
            float sum = hn;
#pragma unroll
            for (int o = 32; o > 0; o >>= 1) sum += __shfl_xor(sum, o);
            if (lane == 0) s_r1[wvi] = sum;
        }
        __syncthreads();
        if (tid < 128) {
            float m = (s_r1[0] + s_r1[1]) * (1.f / 128.f);
            d = hn - m;
            float ss = d * d;
#pragma unroll
            for (int o = 32; o > 0; o >>= 1) ss += __shfl_xor(ss, o);
            if (lane == 0) s_r2[wvi] = ss;
        }
        __syncthreads();
        if (tid < 128) {
            float va = (s_r2[0] + s_r2[1]) * (1.f / 128.f);
            float rs = 1.f / sqrtf(va + 1e-5f);
            float hl = d * rs * gv + bv;
            s_h[tid] = hl;
        }
        __syncthreads();                                  // B4
    }
    float p0 = 0.f, p1 = 0.f;
    if (tid < 128) {
        float hold = s_h[tid];
        p0 = fcW[tid] * hold;
        p1 = fcW[128 + tid] * hold;
#pragma unroll
        for (int o = 32; o > 0; o >>= 1) { p0 += __shfl_xor(p0, o); p1 += __shfl_xor(p1, o); }
        if (lane == 0) { s_r1[wvi] = p0; s_r2[wvi] = p1; }
    }
    __syncthreads();
    if (tid == 0 && q == 0) {
        vout[b * 2 + 0] = s_r1[0] + s_r1[1] + fcb[0];
        vout[b * 2 + 1] = s_r2[0] + s_r2[1] + fcb[1];
    }
}

// ---------------- launcher ----------------
extern "C" void kernel_launch(void* const* d_in, const int* in_sizes, int n_in,
                              void* d_out, int out_size, void* d_ws, size_t ws_size,
                              hipStream_t stream)
{
    const float* x     = (const float*)d_in[0];
    const float* eps   = (const float*)d_in[1];
    const float* W1lv  = (const float*)d_in[2];
    const float* b1lv  = (const float*)d_in[3];
    const float* W2lv  = (const float*)d_in[4];
    const float* b2lv  = (const float*)d_in[5];
    const float* Wmu   = (const float*)d_in[6];
    const float* bmu   = (const float*)d_in[7];
    const float* bn_g  = (const float*)d_in[8];
    const float* bn_b  = (const float*)d_in[9];
    const float* bn_rm = (const float*)d_in[10];
    const float* bn_rv = (const float*)d_in[11];
    const float* Wdec  = (const float*)d_in[12];
    const float* bdec  = (const float*)d_in[13];
    const float* Wih0  = (const float*)d_in[14];
    const float* Whh0  = (const float*)d_in[15];
    const float* bih0  = (const float*)d_in[16];
    const float* bhh0  = (const float*)d_in[17];
    const float* Wih1  = (const float*)d_in[18];
    const float* Whh1  = (const float*)d_in[19];
    const float* bih1  = (const float*)d_in[20];
    const float* bhh1  = (const float*)d_in[21];
    const float* ln_g0 = (const float*)d_in[22];
    const float* ln_b0 = (const float*)d_in[23];
    const float* ln_g1 = (const float*)d_in[24];
    const float* ln_b1 = (const float*)d_in[25];
    const float* fc_W  = (const float*)d_in[26];
    const float* fc_b  = (const float*)d_in[27];

    float* out   = (float*)d_out;
    float* v_out = out;                                   // [64,2]
    float* xrec  = out + 128;                             // [64,1024,256]
    float* mu    = out + 128 + 16777216;                  // [64,1024,128]
    float* lv    = out + 128 + 16777216 + 8388608;        // [64,1024,128]
    float* H0S   = xrec;  // h0 stream parked in xrec slot; decoder overwrites after scan1

    if (ws_size < WS_NEED) return;  // distinctive failure: outputs stay zero
    char* ws = (char*)d_ws;
    float*    XL    = (float*)(ws + WS_XL);
    float*    HENC  = (float*)(ws + WS_HENC);
    float*    GI0   = (float*)(ws + WS_GI0);    // overlays XL+HENC (dead by then)
    float*    XBUF0 = (float*)(ws + WS_XBUF0);
    float*    XBUF1 = (float*)(ws + WS_XBUF1);
    unsigned* CNT0  = (unsigned*)(ws + WS_CNT);
    unsigned* CNT1  = CNT0 + 64 * CNT_STRIDE;
    float*    MUS   = (float*)(ws + WS_MUS);
    float*    MUT   = (float*)(ws + WS_MUT);

    k_prep<<<1, 128, 0, stream>>>(bmu, bn_g, bn_b, bn_rm, bn_rv, MUS, MUT);
    k_xl<<<16384, 256, 0, stream>>>(x, XL, 4194304);
    // encoder
    k_gemm_f32<1,0><<<dim3(512, 4), 256, 0, stream>>>(XL,   W1lv, nullptr, b1lv, HENC, 512, 256, nullptr, nullptr, nullptr);
    k_gemm_f32<0,0><<<dim3(512, 1), 256, 0, stream>>>(HENC, W2lv, nullptr, b2lv, lv,   128, 512, nullptr, nullptr, nullptr);
    k_gemm_f32<2,0><<<dim3(512, 1), 256, 0, stream>>>(XL,   Wmu,  MUS,     MUT,  mu,   128, 256, nullptr, nullptr, nullptr);
    // gi0 GEMM with fused reparameterization (XL/HENC dead -> GI0 overlays them)
    k_gemm_f32<0,1><<<dim3(512, 6), 256, 0, stream>>>(nullptr, Wih0, nullptr, bih0, GI0, 768, 128, mu, lv, eps);
    // reset exchange counters (per launch, graph-capture-safe)
    hipMemsetAsync(CNT0, 0, 32768, stream);
    // sequential scans (4 blocks per batch row, full weight residency)
    k_scan0<<<256, 256, 0, stream>>>(GI0, Whh0, bhh0, ln_g0, ln_b0, H0S, XBUF0, CNT0);
    k_scan1<<<256, 256, 0, stream>>>(H0S, Wih1, Whh1, bih1, bhh1, ln_g1, ln_b1, fc_W, fc_b, v_out, XBUF1, CNT1);
    // decoder with fused reparameterization (overwrites H0S parking with final xrec)
    k_gemm_f32<3,1><<<dim3(512, 2), 256, 0, stream>>>(nullptr, Wdec, nullptr, bdec, xrec, 256, 128, mu, lv, eps);
}

// Round 12
// 8000.654 us; speedup vs baseline: 1.7799x; 1.0582x over previous
//
#include <hip/hip_runtime.h>
#include <cstdint>

typedef unsigned long long u64;

// B=64 S=1024 D_IN=256 D_HID=512 D_LAT=128, GRU: 128->256->128, out 2
#define TOKENS 65536

// ---------------- ws layout (bytes), all f32 ----------------
#define WS_XL    0ULL
#define WS_HENC  67108864ULL
#define WS_GI0   0ULL
#define WS_XBUF0 201326592ULL                    // u64[64][256] = 131072 B (L0 exchange)
#define WS_XBUF1 (201326592ULL + 131072ULL)      // u64[64][128] = 65536 B  (L1 exchange)
#define WS_MUS   (201326592ULL + 196608ULL)
#define WS_MUT   (201326592ULL + 197120ULL)
#define WS_NEED  (201326592ULL + 197632ULL)

// ---------------- prep: fold BN into scale/shift ----------------
__global__ void k_prep(const float* __restrict__ bmu, const float* __restrict__ bng,
                       const float* __restrict__ bnb, const float* __restrict__ bnrm,
                       const float* __restrict__ bnrv,
                       float* __restrict__ mus, float* __restrict__ mut)
{
    int j = threadIdx.x;
    if (j < 128) {
        float s = bng[j] / sqrtf(bnrv[j] + 1e-5f);
        mus[j] = s;
        mut[j] = bmu[j] * s + bnb[j] - bnrm[j] * s;
    }
}

// ---------------- xl = log(softplus(x)), f32 ----------------
__global__ void k_xl(const float* __restrict__ x, float* __restrict__ xl, int n4)
{
    int i = blockIdx.x * blockDim.x + threadIdx.x;
    if (i >= n4) return;
    float4 v = ((const float4*)x)[i];
    float4 o;
    o.x = logf(v.x > 20.f ? v.x : log1pf(expf(v.x)));
    o.y = logf(v.y > 20.f ? v.y : log1pf(expf(v.y)));
    o.z = logf(v.z > 20.f ? v.z : log1pf(expf(v.z)));
    o.w = logf(v.w > 20.f ? v.w : log1pf(expf(v.w)));
    ((float4*)xl)[i] = o;
}

// ---------------- f32 tiled GEMM: C[m,n] = epi(acc*s[n] + t[n]) ----------------
// AZ=1: A computed on the fly as z = mu + eps*exp(0.5*lv)
template<int EPI, int AZ>
__global__ __launch_bounds__(256) void k_gemm_f32(
    const float* __restrict__ A, const float* __restrict__ W,
    const float* __restrict__ svec, const float* __restrict__ tvec,
    float* __restrict__ C, int N, int K,
    const float* __restrict__ ZMU, const float* __restrict__ ZLV, const float* __restrict__ ZEP)
{
    __shared__ float As[32][132];
    __shared__ float Ws[32][132];
    const int tid = threadIdx.x;
    const int tx = tid & 15, ty = tid >> 4;
    const int m0 = blockIdx.x * 128;
    const int n0 = blockIdx.y * 128;
    float acc[8][8];
#pragma unroll
    for (int i = 0; i < 8; ++i)
#pragma unroll
        for (int j = 0; j < 8; ++j) acc[i][j] = 0.f;

    for (int k0 = 0; k0 < K; k0 += 32) {
#pragma unroll
        for (int it = 0; it < 4; ++it) {
            int id = tid + 256 * it;
            int r = id >> 3, c4 = id & 7;
            float4 av;
            if constexpr (AZ) {
                size_t idx = (size_t)(m0 + r) * K + k0 + c4 * 4;
                float4 m4 = *(const float4*)(ZMU + idx);
                float4 l4 = *(const float4*)(ZLV + idx);
                float4 e4 = *(const float4*)(ZEP + idx);
                av.x = m4.x + e4.x * expf(0.5f * l4.x);
                av.y = m4.y + e4.y * expf(0.5f * l4.y);
                av.z = m4.z + e4.z * expf(0.5f * l4.z);
                av.w = m4.w + e4.w * expf(0.5f * l4.w);
            } else {
                av = *(const float4*)(A + (size_t)(m0 + r) * K + k0 + c4 * 4);
            }
            float4 wv = *(const float4*)(W + (size_t)(n0 + r) * K + k0 + c4 * 4);
            As[c4*4+0][r] = av.x; As[c4*4+1][r] = av.y; As[c4*4+2][r] = av.z; As[c4*4+3][r] = av.w;
            Ws[c4*4+0][r] = wv.x; Ws[c4*4+1][r] = wv.y; Ws[c4*4+2][r] = wv.z; Ws[c4*4+3][r] = wv.w;
        }
        __syncthreads();
#pragma unroll
        for (int k = 0; k < 32; ++k) {
            float4 a0 = *(const float4*)&As[k][ty*8];
            float4 a1 = *(const float4*)&As[k][ty*8+4];
            float4 w0 = *(const float4*)&Ws[k][tx*8];
            float4 w1 = *(const float4*)&Ws[k][tx*8+4];
            float ar[8] = {a0.x,a0.y,a0.z,a0.w,a1.x,a1.y,a1.z,a1.w};
            float wr[8] = {w0.x,w0.y,w0.z,w0.w,w1.x,w1.y,w1.z,w1.w};
#pragma unroll
            for (int i = 0; i < 8; ++i)
#pragma unroll
                for (int j = 0; j < 8; ++j) acc[i][j] += ar[i] * wr[j];
        }
        __syncthreads();
    }
#pragma unroll
    for (int i = 0; i < 8; ++i) {
        size_t m = (size_t)m0 + ty*8 + i;
#pragma unroll
        for (int j4 = 0; j4 < 2; ++j4) {
            float o[4];
#pragma unroll
            for (int j = 0; j < 4; ++j) {
                int col = n0 + tx*8 + j4*4 + j;
                float v = acc[i][j4*4+j];
                if (svec) v *= svec[col];
                v += tvec[col];
                if constexpr (EPI == 1) v = fmaxf(v, 0.f);
                if constexpr (EPI == 2) v = fminf(fmaxf(v, -10.f), 10.f);
                if constexpr (EPI == 3) v = expf(v);
                o[j] = v;
            }
            *(float4*)(C + m * N + n0 + tx*8 + j4*4) = *(float4*)o;
        }
    }
}

// ============ tagged exchange: data+tag in ONE relaxed agent-scope u64 ============
// The load that observes the tag IS the data load -> 1 LLC RTT, no counter, no
// fences, no store-drain choreography. Tag = t+1; buffer memset to 0 per launch
// (graph-replay safe). Bounded poll: fails measurably, never hangs.
__device__ __forceinline__ void tstore(u64* p, float v, unsigned tag) {
    u64 w = ((u64)tag << 32) | (u64)__builtin_bit_cast(unsigned, v);
    __hip_atomic_store(p, w, __ATOMIC_RELAXED, __HIP_MEMORY_SCOPE_AGENT);
}
__device__ __forceinline__ float tpoll(const u64* p, unsigned tag) {
    u64 w = 0; int guard = 0;
    do {
        w = __hip_atomic_load(p, __ATOMIC_RELAXED, __HIP_MEMORY_SCOPE_AGENT);
        if ((unsigned)(w >> 32) == tag) break;
        __builtin_amdgcn_s_sleep(1);
    } while (++guard < (1 << 17));
    return __builtin_bit_cast(float, (unsigned)w);
}
// barrier with LDS-only drain: in-flight GLOBAL loads/stores survive (their
// vmcnt waits land at first register use, off the all-block critical path).
__device__ __forceinline__ void rbar() {
    asm volatile("s_waitcnt lgkmcnt(0)" ::: "memory");
    __builtin_amdgcn_s_barrier();
}

// ---------------- scan layer 0: 256 blocks (4 per batch), 256 threads ----------------
__global__ __launch_bounds__(256)
__attribute__((amdgpu_waves_per_eu(1, 1)))
void k_scan0(const float* gi0, const float* wh0, const float* bhh0,
             const float* lg0, const float* lb0,
             float* h0s, u64* xbuf)
{
    const int xcd  = blockIdx.x & 7;
    const int slot = blockIdx.x >> 3;       // 0..31
    const int b    = xcd * 8 + (slot >> 2); // 4 blocks of b land on one XCD
    const int q    = slot & 3;
    const int tid = threadIdx.x;
    const int lane = tid & 63;
    const int wvi  = tid >> 6;

    __shared__ float s_h[256];
    __shared__ float s_g[192];
    __shared__ float s_r1[4], s_r2[4];

    int row = 0;
    if (tid < 192)
        row = (tid < 64) ? (64*q + tid)
            : (tid < 128) ? (256 + 64*q + (tid-64))
                          : (512 + 64*q + (tid-128));
    float4 wr[64];
    float bA = 0.f;
    if (tid < 192) {
        const float4* p = (const float4*)(wh0 + (size_t)row * 256);
#pragma unroll
        for (int i = 0; i < 64; ++i) wr[i] = p[i];
        bA = bhh0[row];
    }
    const float gv = lg0[tid], bv = lb0[tid];
    s_h[tid] = 0.f;
    __syncthreads();

    const float* gbase = gi0 + (size_t)b * 1024 * 768;
    float* hb = h0s + (size_t)b * 1024 * 256;
    u64* xb = xbuf + (size_t)b * 256;

    for (int t = 0; t < 1024; ++t) {
        float gr = 0.f, gz = 0.f, gn = 0.f;
        if (tid >= 192) {               // wave 3: gi0 loads stay in flight across rbar
            const float* gt = gbase + (size_t)t * 768;
            int u = 64*q + (tid - 192);
            gr = gt[u]; gz = gt[256 + u]; gn = gt[512 + u];
        } else {
            // frozen round-4 dot: groups ascending, x->a0 y->a1 z->a2 w->a3, (a0+a1)+(a2+a3)
            float a0 = bA, a1 = 0.f, a2 = 0.f, a3 = 0.f;
            const float4* H = (const float4*)s_h;
#pragma unroll
            for (int i = 0; i < 64; ++i) {
                float4 h4 = H[i];
                a0 += wr[i].x * h4.x; a1 += wr[i].y * h4.y;
                a2 += wr[i].z * h4.z; a3 += wr[i].w * h4.w;
            }
            s_g[tid] = (a0 + a1) + (a2 + a3);
        }
        rbar();                                           // B1 (lgkm only)
        if (tid >= 192) {
            int g = tid - 192;
            int u = 64*q + g;
            float r  = 1.f / (1.f + expf(-(gr + s_g[g])));
            float zg = 1.f / (1.f + expf(-(gz + s_g[64 + g])));
            float nn = tanhf(gn + r * s_g[128 + g]);
            float hn = (1.f - zg) * nn + zg * s_h[u];
            tstore(&xb[u], hn, (unsigned)(t + 1));        // publish: data+tag, one atomic
        }
        // distributed sync: each thread polls its own unit (no barrier needed)
        float hn = tpoll(&xb[tid], (unsigned)(t + 1));
        // LN0 replay (frozen round-4 sequence)
        float sum = hn;
#pragma unroll
        for (int o = 32; o > 0; o >>= 1) sum += __shfl_xor(sum, o);
        if (lane == 0) s_r1[wvi] = sum;
        rbar();                                           // Bmean
        float m = (s_r1[0] + s_r1[1] + s_r1[2] + s_r1[3]) * (1.f / 256.f);
        float d = hn - m;
        float ss = d * d;
#pragma unroll
        for (int o = 32; o > 0; o >>= 1) ss += __shfl_xor(ss, o);
        if (lane == 0) s_r2[wvi] = ss;
        rbar();                                           // Bvar
        float va = (s_r2[0] + s_r2[1] + s_r2[2] + s_r2[3]) * (1.f / 256.f);
        float rs = 1.f / sqrtf(va + 1e-5f);
        float hl = d * rs * gv + bv;
        s_h[tid] = hl;
        if (q == 0) hb[(size_t)t * 256 + tid] = hl;       // store floats across B4
        rbar();                                           // B4
    }
}

// ---------------- scan layer 1: 256 blocks (4 per batch), 256 threads ----------------
// s_x double-buffered; h0[t+1] loads issued at loop top and now genuinely stay
// in flight across the (lgkm-only) B1 -- consumed at the LDS-write in the gates
// phase where the compiler places the vmcnt wait.
__global__ __launch_bounds__(256)
__attribute__((amdgpu_waves_per_eu(1, 1)))
void k_scan1(const float* h0s, const float* wi1, const float* wh1,
             const float* bih1, const float* bhh1,
             const float* lg1, const float* lb1,
             const float* fcW, const float* fcb,
             float* vout, u64* xbuf)
{
    const int xcd  = blockIdx.x & 7;
    const int slot = blockIdx.x >> 3;
    const int b    = xcd * 8 + (slot >> 2);
    const int q    = slot & 3;
    const int tid = threadIdx.x;
    const int lane = tid & 63;
    const int wvi  = tid >> 6;

    __shared__ float s_x[2][256];
    __shared__ float s_h[128];
    __shared__ float s_g[192];
    __shared__ float s_r1[2], s_r2[2];

    float4 wr[64];
    float bB = 0.f;
    if (tid < 96) {
        int jj = tid;
        int row = (jj < 32) ? (32*q + jj) : (jj < 64) ? (128 + 32*q + (jj-32)) : (256 + 32*q + (jj-64));
        const float4* p = (const float4*)(wi1 + (size_t)row * 256);
#pragma unroll
        for (int i = 0; i < 64; ++i) wr[i] = p[i];
        bB = bih1[row];
    } else if (tid < 192) {
        int jj = tid - 96;
        int row = (jj < 32) ? (32*q + jj) : (jj < 64) ? (128 + 32*q + (jj-32)) : (256 + 32*q + (jj-64));
        const float4* p = (const float4*)(wh1 + (size_t)row * 128);
#pragma unroll
        for (int i = 0; i < 32; ++i) wr[i] = p[i];
        bB = bhh1[row];
    }
    float gv = 0.f, bv = 0.f;
    if (tid < 128) { gv = lg1[tid]; bv = lb1[tid]; s_h[tid] = 0.f; }
    const float4* xb4 = (const float4*)(h0s + (size_t)b * 1024 * 256);
    if (tid < 64) ((float4*)s_x[0])[tid] = xb4[tid];      // stage t=0
    __syncthreads();

    u64* xb = xbuf + (size_t)b * 128;

    for (int t = 0; t < 1024; ++t) {
        const int cur = t & 1, nxt = cur ^ 1;
        // early issue: h0[t+1] loads at loop top (in flight across rbar B1)
        float4 st0, st1;
        const bool stg = (tid >= 224) && (t + 1 < 1024);
        if (stg) {
            int k = tid - 224;
            st0 = xb4[(size_t)(t+1) * 64 + k];
            st1 = xb4[(size_t)(t+1) * 64 + k + 32];
        }
        if (tid < 96) {
            // frozen scan1 ih dot
            float a0 = bB, a1 = 0.f, a2 = 0.f, a3 = 0.f;
            const float4* X = (const float4*)s_x[cur];
#pragma unroll
            for (int i = 0; i < 64; ++i) {
                float4 h4 = X[i];
                a0 += wr[i].x * h4.x; a1 += wr[i].y * h4.y;
                a2 += wr[i].z * h4.z; a3 += wr[i].w * h4.w;
            }
            s_g[tid] = (a0 + a1) + (a2 + a3);
        } else if (tid < 192) {
            float a0 = bB, a1 = 0.f, a2 = 0.f, a3 = 0.f;
            const float4* Hh = (const float4*)s_h;
#pragma unroll
            for (int i = 0; i < 32; ++i) {
                float4 h4 = Hh[i];
                a0 += wr[i].x * h4.x; a1 += wr[i].y * h4.y;
                a2 += wr[i].z * h4.z; a3 += wr[i].w * h4.w;
            }
            s_g[96 + (tid - 96)] = (a0 + a1) + (a2 + a3);
        }
        rbar();                                           // B1 (lgkm only)
        if (tid >= 192 && tid < 224) {
            int g = tid - 192;
            int u = 32*q + g;
            float r  = 1.f / (1.f + expf(-(s_g[g]      + s_g[96 + g])));
            float zg = 1.f / (1.f + expf(-(s_g[32 + g] + s_g[128 + g])));
            float nn = tanhf(s_g[64 + g] + r * s_g[160 + g]);
            float hn = (1.f - zg) * nn + zg * s_h[u];
            tstore(&xb[u], hn, (unsigned)(t + 1));
        } else if (stg) {                                 // write staged h0[t+1]
            int k = tid - 224;
            ((float4*)s_x[nxt])[k]      = st0;
            ((float4*)s_x[nxt])[k + 32] = st1;
        }
        // distributed sync: tid<128 poll their unit
        float hn = 0.f, d = 0.f;
        if (tid < 128) {
            hn = tpoll(&xb[tid], (unsigned)(t + 1));
            float sum = hn;
#pragma unroll
            for (int o = 32; o > 0; o >>= 1) sum += __shfl_xor(sum, o);
            if (lane == 0) s_r1[wvi] = sum;
        }
        rbar();                                           // Bmean
        if (tid < 128) {
            float m = (s_r1[0] + s_r1[1]) * (1.f / 128.f);
            d = hn - m;
            float ss = d * d;
#pragma unroll
            for (int o = 32; o > 0; o >>= 1) ss += __shfl_xor(ss, o);
            if (lane == 0) s_r2[wvi] = ss;
        }
        rbar();                                           // Bvar
        if (tid < 128) {
            float va = (s_r2[0] + s_r2[1]) * (1.f / 128.f);
            float rs = 1.f / sqrtf(va + 1e-5f);
            float hl = d * rs * gv + bv;
            s_h[tid] = hl;
        }
        rbar();                                           // B4
    }
    float p0 = 0.f, p1 = 0.f;
    if (tid < 128) {
        float hold = s_h[tid];
        p0 = fcW[tid] * hold;
        p1 = fcW[128 + tid] * hold;
#pragma unroll
        for (int o = 32; o > 0; o >>= 1) { p0 += __shfl_xor(p0, o); p1 += __shfl_xor(p1, o); }
        if (lane == 0) { s_r1[wvi] = p0; s_r2[wvi] = p1; }
    }
    __syncthreads();
    if (tid == 0 && q == 0) {
        vout[b * 2 + 0] = s_r1[0] + s_r1[1] + fcb[0];
        vout[b * 2 + 1] = s_r2[0] + s_r2[1] + fcb[1];
    }
}

// ---------------- launcher ----------------
extern "C" void kernel_launch(void* const* d_in, const int* in_sizes, int n_in,
                              void* d_out, int out_size, void* d_ws, size_t ws_size,
                              hipStream_t stream)
{
    const float* x     = (const float*)d_in[0];
    const float* eps   = (const float*)d_in[1];
    const float* W1lv  = (const float*)d_in[2];
    const float* b1lv  = (const float*)d_in[3];
    const float* W2lv  = (const float*)d_in[4];
    const float* b2lv  = (const float*)d_in[5];
    const float* Wmu   = (const float*)d_in[6];
    const float* bmu   = (const float*)d_in[7];
    const float* bn_g  = (const float*)d_in[8];
    const float* bn_b  = (const float*)d_in[9];
    const float* bn_rm = (const float*)d_in[10];
    const float* bn_rv = (const float*)d_in[11];
    const float* Wdec  = (const float*)d_in[12];
    const float* bdec  = (const float*)d_in[13];
    const float* Wih0  = (const float*)d_in[14];
    const float* Whh0  = (const float*)d_in[15];
    const float* bih0  = (const float*)d_in[16];
    const float* bhh0  = (const float*)d_in[17];
    const float* Wih1  = (const float*)d_in[18];
    const float* Whh1  = (const float*)d_in[19];
    const float* bih1  = (const float*)d_in[20];
    const float* bhh1  = (const float*)d_in[21];
    const float* ln_g0 = (const float*)d_in[22];
    const float* ln_b0 = (const float*)d_in[23];
    const float* ln_g1 = (const float*)d_in[24];
    const float* ln_b1 = (const float*)d_in[25];
    const float* fc_W  = (const float*)d_in[26];
    const float* fc_b  = (const float*)d_in[27];

    float* out   = (float*)d_out;
    float* v_out = out;                                   // [64,2]
    float* xrec  = out + 128;                             // [64,1024,256]
    float* mu    = out + 128 + 16777216;                  // [64,1024,128]
    float* lv    = out + 128 + 16777216 + 8388608;        // [64,1024,128]
    float* H0S   = xrec;  // h0 stream parked in xrec slot; decoder overwrites after scan1

    if (ws_size < WS_NEED) return;  // distinctive failure: outputs stay zero
    char* ws = (char*)d_ws;
    float* XL    = (float*)(ws + WS_XL);
    float* HENC  = (float*)(ws + WS_HENC);
    float* GI0   = (float*)(ws + WS_GI0);    // overlays XL+HENC (dead by then)
    u64*   XBUF0 = (u64*)(ws + WS_XBUF0);
    u64*   XBUF1 = (u64*)(ws + WS_XBUF1);
    float* MUS   = (float*)(ws + WS_MUS);
    float* MUT   = (float*)(ws + WS_MUT);

    k_prep<<<1, 128, 0, stream>>>(bmu, bn_g, bn_b, bn_rm, bn_rv, MUS, MUT);
    k_xl<<<16384, 256, 0, stream>>>(x, XL, 4194304);
    // encoder
    k_gemm_f32<1,0><<<dim3(512, 4), 256, 0, stream>>>(XL,   W1lv, nullptr, b1lv, HENC, 512, 256, nullptr, nullptr, nullptr);
    k_gemm_f32<0,0><<<dim3(512, 1), 256, 0, stream>>>(HENC, W2lv, nullptr, b2lv, lv,   128, 512, nullptr, nullptr, nullptr);
    k_gemm_f32<2,0><<<dim3(512, 1), 256, 0, stream>>>(XL,   Wmu,  MUS,     MUT,  mu,   128, 256, nullptr, nullptr, nullptr);
    // gi0 GEMM with fused reparameterization (XL/HENC dead -> GI0 overlays them)
    k_gemm_f32<0,1><<<dim3(512, 6), 256, 0, stream>>>(nullptr, Wih0, nullptr, bih0, GI0, 768, 128, mu, lv, eps);
    // reset exchange tag buffers (per launch; tag 0 != any step tag 1..1024)
    hipMemsetAsync(XBUF0, 0, 196608, stream);
    // sequential scans (4 blocks per batch row, tagged-atomic exchange)
    k_scan0<<<256, 256, 0, stream>>>(GI0, Whh0, bhh0, ln_g0, ln_b0, H0S, XBUF0);
    k_scan1<<<256, 256, 0, stream>>>(H0S, Wih1, Whh1, bih1, bhh1, ln_g1, ln_b1, fc_W, fc_b, v_out, XBUF1);
    // decoder with fused reparameterization (overwrites H0S parking with final xrec)
    k_gemm_f32<3,1><<<dim3(512, 2), 256, 0, stream>>>(nullptr, Wdec, nullptr, bdec, xrec, 256, 128, mu, lv, eps);
}